// Round 9
// baseline (161.965 us; speedup 1.0000x reference)
//
#include <hip/hip_runtime.h>
#include <hip/hip_bf16.h>

typedef __bf16 bf16x8 __attribute__((ext_vector_type(8)));
typedef float  f32x4  __attribute__((ext_vector_type(4)));

#define BS 64       // rotation block size
#define RB 64       // number of rotation blocks
#define NELEM 2016  // strict upper-triangle element count
#define DD 4096     // feature dim
#define MROWS 16384 // 4 * 4096 rows

// ---------------------------------------------------------------------------
// Kernel A (r6-verified row-split): R = I + 2Q + 2Q^2 + 2Q^3 + 2Q^4, emitted
// bf16 in packed fragment order:
//   Rpk[((rblk*8 + kf*4 + n)*64 + lane)*8 + jj] =
//       bf16( R[32*kf + 8*(lane>>4) + jj][16*n + (lane&15)] )
// 4 blocks per rblk (256 blocks, full chip). ALL loops fully unrolled ->
// compile-time indices -> registers (rule #20).
// ---------------------------------------------------------------------------
__global__ __launch_bounds__(256) void rot_kernel(const float* __restrict__ w,
                                                  __bf16* __restrict__ Rpk) {
    const int bid   = blockIdx.x;
    const int blk   = bid >> 2;          // rblk
    const int rbase = (bid & 3) * 16;    // this block's 16 rows of R
    const int t     = threadIdx.x;
    __shared__ float Q [BS * BS];
    __shared__ float T0[16 * BS];
    __shared__ float T1[16 * BS];
    const float* wb = w + blk * NELEM;

    for (int e = t; e < BS * BS; e += 256) {
        const int i = e >> 6, j = e & 63;
        float v = 0.f;
        if (i < j)      v =  wb[63 * i - (i * (i - 1)) / 2 + (j - i - 1)];
        else if (i > j) v = -wb[63 * j - (j * (j - 1)) / 2 + (i - j - 1)];
        Q[e] = v;
    }
    __syncthreads();

    const int j  = t & 63;         // column
    const int s4 = (t >> 6) * 4;   // first of this thread's 4 rows (relative)

    float qcol[BS];
#pragma unroll
    for (int k = 0; k < BS; ++k) qcol[k] = Q[k * BS + j];

    float racc[4];
#pragma unroll
    for (int s = 0; s < 4; ++s) {
        const int i = rbase + s4 + s;
        racc[s] = (i == j ? 1.f : 0.f) + 2.f * Q[i * BS + j];
    }

#pragma unroll
    for (int s = 0; s < 4; ++s) {
        const int i = rbase + s4 + s;
        float sum = 0.f;
#pragma unroll
        for (int k = 0; k < BS; ++k) sum += Q[i * BS + k] * qcol[k];
        T0[(s4 + s) * BS + j] = sum;
        racc[s] += 2.f * sum;
    }
    __syncthreads();

#pragma unroll
    for (int s = 0; s < 4; ++s) {
        const int r = s4 + s;
        float sum = 0.f;
#pragma unroll
        for (int k = 0; k < BS; ++k) sum += T0[r * BS + k] * qcol[k];
        T1[r * BS + j] = sum;
        racc[s] += 2.f * sum;
    }
    __syncthreads();

#pragma unroll
    for (int s = 0; s < 4; ++s) {
        const int r = s4 + s;
        float sum = 0.f;
#pragma unroll
        for (int k = 0; k < BS; ++k) sum += T1[r * BS + k] * qcol[k];
        racc[s] += 2.f * sum;
    }

#pragma unroll
    for (int s = 0; s < 4; ++s) {
        const int i  = rbase + s4 + s;
        const int kf = i >> 5;
        const int g  = (i >> 3) & 3;
        const int jj = i & 7;
        const int lane = 16 * g + (j & 15);
        const int n    = j >> 4;
        Rpk[(size_t)((blk * 8 + kf * 4 + n) * 64 + lane) * 8 + jj] = (__bf16)racc[s];
    }
}

// ---------------------------------------------------------------------------
// Kernel B (COLUMN-SWEEP): wave owns 16 FIXED rows and sweeps 16 consecutive
// rblks (one quadrant of the row). Consecutive iterations touch the NEXT
// 256B of the SAME 16 rows for both the x-read and y-write streams ->
// per-row sequential DRAM page behavior (r6 never revisited a row; every
// 256B visit was an isolated page activation; system measured latency-
// queued at 57% of copy BW with all pipes idle).
// R frags for the current rblk are prefetched per iteration from Rpk
// (512KB, L2/L3-resident). MFMA + scalar-nt-store structure byte-identical
// to r6 (measured best). No LDS, no barriers. All loop indices compile-time.
// ---------------------------------------------------------------------------
__global__ __launch_bounds__(256) void apply_kernel(const float* __restrict__ x,
                                                    const __bf16* __restrict__ Rpk,
                                                    float* __restrict__ y) {
    const int tid  = threadIdx.x;
    const int l    = tid & 63;
    const int wv   = tid >> 6;
    const int W    = blockIdx.x * 4 + wv;
    const int qd   = W & 3;            // column quadrant: rblks qd*16..qd*16+15
    const int rg   = W >> 2;           // 0..1023: 16-row group
    const int g    = l >> 4;
    const int c    = l & 15;

    const long rowbase = (long)rg * 16;
    const long colbase = qd * 1024;    // quadrant's first float column

    // Lane's x source for iteration rr: row = rowbase + (l&15),
    // cols colbase + rr*64 + g*8 (+32 for kf=1).
    const float* xlane = x + (rowbase + (l & 15)) * (long)DD + colbase + g * 8;

    // R fragment stream: rblk = qd*16 + rr; frag vectors at
    // ((rblk*8 + kf*4 + n)*64 + l).
    const bf16x8* rp = reinterpret_cast<const bf16x8*>(Rpk)
                     + ((size_t)(qd * 16) * 8) * 64 + l;

    const f32x4 zero = {0.f, 0.f, 0.f, 0.f};

    // Prologue: load iteration 0's x and R frags.
    f32x4 v[4], vn[4];
#pragma unroll
    for (int q = 0; q < 4; ++q)
        v[q] = *reinterpret_cast<const f32x4*>(xlane + (q >> 1) * 32 + (q & 1) * 4);

    bf16x8 bfc[2][4], bfn[2][4];
#pragma unroll
    for (int kf = 0; kf < 2; ++kf)
#pragma unroll
        for (int n = 0; n < 4; ++n)
            bfc[kf][n] = rp[(kf * 4 + n) * 64];

#pragma unroll
    for (int rr = 0; rr < 16; ++rr) {
        // Prefetch next iteration's x (next 256B of the same rows) and the
        // next rblk's R fragments (L2-resident).
        if (rr + 1 < 16) {
            const float* xp = xlane + (rr + 1) * 64;
#pragma unroll
            for (int q = 0; q < 4; ++q)
                vn[q] = *reinterpret_cast<const f32x4*>(xp + (q >> 1) * 32 + (q & 1) * 4);
            const bf16x8* rpn = rp + (size_t)(rr + 1) * 512;
#pragma unroll
            for (int kf = 0; kf < 2; ++kf)
#pragma unroll
                for (int n = 0; n < 4; ++n)
                    bfn[kf][n] = rpn[(kf * 4 + n) * 64];
        }

        // Convert to bf16 A-fragments (elements jj <-> k = 32kf + 8g + jj).
        bf16x8 a0, a1;
#pragma unroll
        for (int e = 0; e < 4; ++e) {
            a0[e]     = (__bf16)v[0][e];
            a0[e + 4] = (__bf16)v[1][e];
            a1[e]     = (__bf16)v[2][e];
            a1[e + 4] = (__bf16)v[3][e];
        }

        f32x4 acc[4];
#pragma unroll
        for (int n = 0; n < 4; ++n)
            acc[n] = __builtin_amdgcn_mfma_f32_16x16x32_bf16(a0, bfc[0][n], zero, 0, 0, 0);
#pragma unroll
        for (int n = 0; n < 4; ++n)
            acc[n] = __builtin_amdgcn_mfma_f32_16x16x32_bf16(a1, bfc[1][n], acc[n], 0, 0, 0);

        // Store: lane holds rows 4g+i, col c+16n of this 16x64 tile.
        // Scalar nontemporal stores (measured best; 16 adjacent lanes =
        // full 64B line per 16-lane group).
        float* yl = y + (rowbase + 4 * g) * (long)DD + colbase + rr * 64 + c;
#pragma unroll
        for (int n = 0; n < 4; ++n)
#pragma unroll
            for (int i = 0; i < 4; ++i)
                __builtin_nontemporal_store(acc[n][i], yl + (long)i * DD + n * 16);

        if (rr + 1 < 16) {
#pragma unroll
            for (int q = 0; q < 4; ++q) v[q] = vn[q];
#pragma unroll
            for (int kf = 0; kf < 2; ++kf)
#pragma unroll
                for (int n = 0; n < 4; ++n)
                    bfc[kf][n] = bfn[kf][n];
        }
    }
}

extern "C" void kernel_launch(void* const* d_in, const int* in_sizes, int n_in,
                              void* d_out, int out_size, void* d_ws, size_t ws_size,
                              hipStream_t stream) {
    (void)in_sizes; (void)n_in; (void)out_size; (void)ws_size;
    const float* x = (const float*)d_in[0];
    const float* w = (const float*)d_in[1];
    float* y = (float*)d_out;
    __bf16* Rpk = (__bf16*)d_ws;   // 64 rblk * 8 frags * 64 lanes * 8 bf16 = 512 KB

    rot_kernel<<<RB * 4, 256, 0, stream>>>(w, Rpk);

    const int waves  = (MROWS / 16) * 4;   // 1024 row-groups x 4 quadrants
    const int blocks = waves / 4;          // 1024 blocks of 256 threads
    apply_kernel<<<blocks, 256, 0, stream>>>(x, Rpk, y);
}

// Round 10
// 117.890 us; speedup vs baseline: 1.3739x; 1.3739x over previous
//
#include <hip/hip_runtime.h>
#include <hip/hip_bf16.h>

typedef __bf16 bf16x8 __attribute__((ext_vector_type(8)));
typedef float  f32x4  __attribute__((ext_vector_type(4)));

#define BS 64       // rotation block size
#define RB 64       // number of rotation blocks
#define NELEM 2016  // strict upper-triangle element count
#define DD 4096     // feature dim
#define MROWS 16384 // 4 * 4096 rows
#define TILES 8     // 16-row tiles per wave

// ---------------------------------------------------------------------------
// Kernel A (r6-verified row-split): R = I + 2Q + 2Q^2 + 2Q^3 + 2Q^4, emitted
// bf16 in packed fragment order:
//   Rpk[((rblk*8 + kf*4 + n)*64 + lane)*8 + jj] =
//       bf16( R[32*kf + 8*(lane>>4) + jj][16*n + (lane&15)] )
// Row-block recurrence: 4 blocks per rblk (256 blocks, full chip).
// ALL loops fully unrolled -> compile-time indices -> registers (rule #20).
// ---------------------------------------------------------------------------
__global__ __launch_bounds__(256) void rot_kernel(const float* __restrict__ w,
                                                  __bf16* __restrict__ Rpk) {
    const int bid   = blockIdx.x;
    const int blk   = bid >> 2;          // rblk
    const int rbase = (bid & 3) * 16;    // this block's 16 rows of R
    const int t     = threadIdx.x;
    __shared__ float Q [BS * BS];
    __shared__ float T0[16 * BS];
    __shared__ float T1[16 * BS];
    const float* wb = w + blk * NELEM;

    for (int e = t; e < BS * BS; e += 256) {
        const int i = e >> 6, j = e & 63;
        float v = 0.f;
        if (i < j)      v =  wb[63 * i - (i * (i - 1)) / 2 + (j - i - 1)];
        else if (i > j) v = -wb[63 * j - (j * (j - 1)) / 2 + (i - j - 1)];
        Q[e] = v;
    }
    __syncthreads();

    const int j  = t & 63;         // column
    const int s4 = (t >> 6) * 4;   // first of this thread's 4 rows (relative)

    float qcol[BS];
#pragma unroll
    for (int k = 0; k < BS; ++k) qcol[k] = Q[k * BS + j];

    float racc[4];
#pragma unroll
    for (int s = 0; s < 4; ++s) {
        const int i = rbase + s4 + s;
        racc[s] = (i == j ? 1.f : 0.f) + 2.f * Q[i * BS + j];
    }

#pragma unroll
    for (int s = 0; s < 4; ++s) {
        const int i = rbase + s4 + s;
        float sum = 0.f;
#pragma unroll
        for (int k = 0; k < BS; ++k) sum += Q[i * BS + k] * qcol[k];
        T0[(s4 + s) * BS + j] = sum;
        racc[s] += 2.f * sum;
    }
    __syncthreads();

#pragma unroll
    for (int s = 0; s < 4; ++s) {
        const int r = s4 + s;
        float sum = 0.f;
#pragma unroll
        for (int k = 0; k < BS; ++k) sum += T0[r * BS + k] * qcol[k];
        T1[r * BS + j] = sum;
        racc[s] += 2.f * sum;
    }
    __syncthreads();

#pragma unroll
    for (int s = 0; s < 4; ++s) {
        const int r = s4 + s;
        float sum = 0.f;
#pragma unroll
        for (int k = 0; k < BS; ++k) sum += T1[r * BS + k] * qcol[k];
        racc[s] += 2.f * sum;
    }

#pragma unroll
    for (int s = 0; s < 4; ++s) {
        const int i  = rbase + s4 + s;
        const int kf = i >> 5;
        const int g  = (i >> 3) & 3;
        const int jj = i & 7;
        const int lane = 16 * g + (j & 15);
        const int n    = j >> 4;
        Rpk[(size_t)((blk * 8 + kf * 4 + n) * 64 + lane) * 8 + jj] = (__bf16)racc[s];
    }
}

// ---------------------------------------------------------------------------
// Kernel B: MEASURED-BEST apply (r6: 117.9us total, apply ~113us).
// y = x . R per 64-block via mfma_f32_16x16x32_bf16, non-swapped operands,
// scalar nontemporal stores. R entirely in registers (8 B-frags); X
// global->reg in A-frag order (each byte read exactly once); no LDS, no
// barriers. Refuted alternatives (do NOT reintroduce):
//   r4/r5 swap+float4 stores: +17us (lane->16KB-stride store scatter)
//   r7 LDS staging (4x fewer load txns): +3us (not TA-bound)
//   r8 512-thr lockstep barrier: +12us
//   r9 column-sweep (page locality): +44us (VGPR 96 -> occupancy 19%)
// Gap to copy BW (~57%) is the memory system's behavior on this 2D access
// shape; five mechanism-distinct probes all failed to close it.
// ---------------------------------------------------------------------------
__global__ __launch_bounds__(256) void apply_kernel(const float* __restrict__ x,
                                                    const __bf16* __restrict__ Rpk,
                                                    float* __restrict__ y) {
    const int tid  = threadIdx.x;
    const int l    = tid & 63;
    const int W    = blockIdx.x * 4 + (tid >> 6);
    const int rblk = W & 63;
    const int rg   = W >> 6;          // 0..127 row-groups of 128 rows
    const int g    = l >> 4;
    const int c    = l & 15;

    // Load the 8 B-fragments of R[rblk] (coalesced 16B per lane).
    bf16x8 bfrag[2][4];
    const bf16x8* rp = reinterpret_cast<const bf16x8*>(Rpk) + (size_t)rblk * 8 * 64 + l;
#pragma unroll
    for (int kf = 0; kf < 2; ++kf)
#pragma unroll
        for (int n = 0; n < 4; ++n)
            bfrag[kf][n] = rp[(kf * 4 + n) * 64];

    const long rowbase = (long)rg * (TILES * 16);
    // Lane's A-frag source: row = l&15 within tile, k-bytes at g*8 (+kf*32).
    const float* xlane = x + (rowbase + (l & 15)) * (long)DD + rblk * 64 + g * 8;

    const f32x4 zero = {0.f, 0.f, 0.f, 0.f};

    f32x4 v[4], vn[4];
#pragma unroll
    for (int q = 0; q < 4; ++q)
        v[q] = *reinterpret_cast<const f32x4*>(xlane + (q >> 1) * 32 + (q & 1) * 4);

#pragma unroll
    for (int t = 0; t < TILES; ++t) {
        // Prefetch next tile's X (independent of compute below).
        if (t + 1 < TILES) {
            const float* xp = xlane + (long)(t + 1) * 16 * DD;
#pragma unroll
            for (int q = 0; q < 4; ++q)
                vn[q] = *reinterpret_cast<const f32x4*>(xp + (q >> 1) * 32 + (q & 1) * 4);
        }

        // Convert to bf16 A-fragments (elements jj <-> k = 32kf + 8g + jj).
        bf16x8 a0, a1;
#pragma unroll
        for (int e = 0; e < 4; ++e) {
            a0[e]     = (__bf16)v[0][e];
            a0[e + 4] = (__bf16)v[1][e];
            a1[e]     = (__bf16)v[2][e];
            a1[e + 4] = (__bf16)v[3][e];
        }

        f32x4 acc[4];
#pragma unroll
        for (int n = 0; n < 4; ++n)
            acc[n] = __builtin_amdgcn_mfma_f32_16x16x32_bf16(a0, bfrag[0][n], zero, 0, 0, 0);
#pragma unroll
        for (int n = 0; n < 4; ++n)
            acc[n] = __builtin_amdgcn_mfma_f32_16x16x32_bf16(a1, bfrag[1][n], acc[n], 0, 0, 0);

        // Store: lane holds rows 4g+i, col c+16n of this 16x64 tile.
        // Nontemporal scalar stores: 16 adjacent lanes = full 64B line.
        float* yl = y + (rowbase + t * 16 + 4 * g) * (long)DD + rblk * 64 + c;
#pragma unroll
        for (int n = 0; n < 4; ++n)
#pragma unroll
            for (int i = 0; i < 4; ++i)
                __builtin_nontemporal_store(acc[n][i], yl + (long)i * DD + n * 16);

        if (t + 1 < TILES) {
#pragma unroll
            for (int q = 0; q < 4; ++q) v[q] = vn[q];
        }
    }
}

extern "C" void kernel_launch(void* const* d_in, const int* in_sizes, int n_in,
                              void* d_out, int out_size, void* d_ws, size_t ws_size,
                              hipStream_t stream) {
    (void)in_sizes; (void)n_in; (void)out_size; (void)ws_size;
    const float* x = (const float*)d_in[0];
    const float* w = (const float*)d_in[1];
    float* y = (float*)d_out;
    __bf16* Rpk = (__bf16*)d_ws;   // 64 rblk * 8 frags * 64 lanes * 8 bf16 = 512 KB

    rot_kernel<<<RB * 4, 256, 0, stream>>>(w, Rpk);

    const int waves  = RB * (MROWS / (TILES * 16));  // 64 * 128 = 8192
    const int blocks = waves / 4;                    // 2048 blocks of 256 thr
    apply_kernel<<<blocks, 256, 0, stream>>>(x, Rpk, y);
}